// Round 6
// baseline (5525.067 us; speedup 1.0000x reference)
//
#include <hip/hip_runtime.h>
#include <hip/hip_bf16.h>
#include <math.h>

// Problem constants
#define NPB  192            // N*P = 32*6
#define CCH  128
#define TT   64
#define VV   25
#define PIX  1600           // T*V
#define SS   3
#define EPC  307200.0f      // elems per channel for BN (192*1600)
static const size_t ETOT = (size_t)NPB * CCH * PIX;   // 39,321,600

typedef __attribute__((ext_vector_type(4))) float f32x4;
typedef __attribute__((ext_vector_type(8))) short short8;

__device__ __forceinline__ ushort f2bf(float f) {
    __hip_bfloat16 h = __float2bfloat16(f);
    return __builtin_bit_cast(unsigned short, h);
}
__device__ __forceinline__ float bf2f(ushort u) {
    unsigned int x = ((unsigned int)u) << 16;
    return __builtin_bit_cast(float, x);
}

// ---------------------------------------------------------------------------
// Weight prep: permute w_in rows to [q0|k0|q1|k1|q2|k2] (64-chunks), cvt bf16
// ---------------------------------------------------------------------------
__global__ void wprep(const float* __restrict__ w_in, const float* __restrict__ b_in,
                      const float* __restrict__ w_out, const float* __restrict__ w_ff,
                      ushort* __restrict__ Wp, float* __restrict__ bp,
                      ushort* __restrict__ Wo, ushort* __restrict__ Wf) {
    int i = blockIdx.x * 256 + threadIdx.x;   // grid covers 49152
    if (i < 192 * 128) {
        int r = i >> 7, c = i & 127;
        int s = r / 64, j = r % 64;
        int src = (j < 32) ? (s * 32 + j) : (96 + s * 32 + (j - 32));
        Wp[i] = f2bf(w_in[src * 128 + c]);
        if (c == 0) bp[r] = b_in[src];
    }
    if (i < 128 * 384) Wo[i] = f2bf(w_out[i]);
    if (i < 128 * 128) Wf[i] = f2bf(w_ff[i]);
}

// ---------------------------------------------------------------------------
// remap: xr[np][c][v*64+t] = bf16(x[np][c][t*25+v])
// ---------------------------------------------------------------------------
__global__ void remap_x(const float* __restrict__ x, ushort* __restrict__ xr) {
    size_t o = ((size_t)blockIdx.x * 256 + threadIdx.x) * 4;
    size_t row = o / PIX;
    int p = (int)(o % PIX);           // v*64 + t0, t0 multiple of 4
    int v = p >> 6, t0 = p & 63;
    const float* xp = x + row * PIX;
    uint2 u;
    u.x = (uint)f2bf(xp[(t0 + 0) * 25 + v]) | ((uint)f2bf(xp[(t0 + 1) * 25 + v]) << 16);
    u.y = (uint)f2bf(xp[(t0 + 2) * 25 + v]) | ((uint)f2bf(xp[(t0 + 3) * 25 + v]) << 16);
    *(uint2*)(xr + o) = u;
}

// ---------------------------------------------------------------------------
// MFMA conv GEMM: out[np][obase+o][pix] = bias + sum_{k<128} W[o][k]*in[np][k][pix]
//  optional per-channel stats (sum, sumsq) accumulation via atomics
// ---------------------------------------------------------------------------
__global__ __launch_bounds__(256)
void gemm_conv(const void* __restrict__ inp, int in_bf16,
               const ushort* __restrict__ W, int ldw,
               const float* __restrict__ bias,
               void* __restrict__ outp, int out_bf16, int out_ch,
               float* __restrict__ stats)
{
    __shared__ ushort Wt[64 * 72];
    __shared__ ushort Xt[128 * 72];
    const int np = blockIdx.x;
    const int pixbase = blockIdx.y * 128;
    const int obase = blockIdx.z * 64;
    const int tid = threadIdx.x;
    const int wave = tid >> 6, lane = tid & 63;
    const int quad = lane >> 4, l16 = lane & 15;
    const int wPix = wave * 32;

    f32x4 acc[4][2];
#pragma unroll
    for (int ms = 0; ms < 4; ++ms) {
        float bv[4];
#pragma unroll
        for (int r = 0; r < 4; ++r) {
            int ol = ms * 16 + quad * 4 + r;
            bv[r] = bias ? bias[obase + ol] : 0.f;
        }
#pragma unroll
        for (int ns = 0; ns < 2; ++ns)
#pragma unroll
            for (int r = 0; r < 4; ++r) acc[ms][ns][r] = bv[r];
    }

    const ushort* inb = (const ushort*)inp;
    const float* inf = (const float*)inp;
    const size_t in_off = (size_t)np * 128 * PIX;

    for (int kc = 0; kc < 2; ++kc) {
        const int kbase = kc * 64;
        {
            int o = tid >> 2, seg = tid & 3;
            const ushort* src = W + (size_t)(obase + o) * ldw + kbase + seg * 16;
            uint4 a = *(const uint4*)src;
            uint4 b = *(const uint4*)(src + 8);
            *(uint4*)&Wt[o * 72 + seg * 16] = a;
            *(uint4*)&Wt[o * 72 + seg * 16 + 8] = b;
        }
        {
            int cp = tid & 31, rq = tid >> 5;
            int c = cp * 2;
            int p0 = rq * 16;
            bool valid = (pixbase + p0) < PIX;
            if (in_bf16) {
                uint ra[8], rb[8];
                if (valid) {
                    const ushort* s0 = inb + in_off + (size_t)(kbase + c) * PIX + pixbase + p0;
                    const ushort* s1 = s0 + PIX;
                    *(uint4*)&ra[0] = *(const uint4*)s0;
                    *(uint4*)&ra[4] = *(const uint4*)(s0 + 8);
                    *(uint4*)&rb[0] = *(const uint4*)s1;
                    *(uint4*)&rb[4] = *(const uint4*)(s1 + 8);
                } else {
#pragma unroll
                    for (int h = 0; h < 8; ++h) { ra[h] = 0; rb[h] = 0; }
                }
#pragma unroll
                for (int h = 0; h < 8; ++h) {
                    uint lo = ra[h], hi = rb[h];
                    *(uint*)&Xt[(p0 + 2 * h) * 72 + c] = (lo & 0xffffu) | (hi << 16);
                    *(uint*)&Xt[(p0 + 2 * h + 1) * 72 + c] = (lo >> 16) | (hi & 0xffff0000u);
                }
            } else {
                if (valid) {
                    const float* s0 = inf + in_off + (size_t)(kbase + c) * PIX + pixbase + p0;
                    const float* s1 = s0 + PIX;
#pragma unroll
                    for (int b4 = 0; b4 < 4; ++b4) {
                        float4 u = ((const float4*)s0)[b4];
                        float4 w4 = ((const float4*)s1)[b4];
                        int p = p0 + b4 * 4;
                        *(uint*)&Xt[(p + 0) * 72 + c] = (uint)f2bf(u.x) | ((uint)f2bf(w4.x) << 16);
                        *(uint*)&Xt[(p + 1) * 72 + c] = (uint)f2bf(u.y) | ((uint)f2bf(w4.y) << 16);
                        *(uint*)&Xt[(p + 2) * 72 + c] = (uint)f2bf(u.z) | ((uint)f2bf(w4.z) << 16);
                        *(uint*)&Xt[(p + 3) * 72 + c] = (uint)f2bf(u.w) | ((uint)f2bf(w4.w) << 16);
                    }
                } else {
#pragma unroll
                    for (int h = 0; h < 16; ++h) *(uint*)&Xt[(p0 + h) * 72 + c] = 0;
                }
            }
        }
        __syncthreads();
#pragma unroll
        for (int ks = 0; ks < 2; ++ks) {
            const int kk = ks * 32;
            short8 a[4], b[2];
#pragma unroll
            for (int ms = 0; ms < 4; ++ms)
                a[ms] = *(const short8*)&Wt[(ms * 16 + l16) * 72 + kk + quad * 8];
#pragma unroll
            for (int ns = 0; ns < 2; ++ns)
                b[ns] = *(const short8*)&Xt[(wPix + ns * 16 + l16) * 72 + kk + quad * 8];
#pragma unroll
            for (int ms = 0; ms < 4; ++ms)
#pragma unroll
                for (int ns = 0; ns < 2; ++ns)
                    acc[ms][ns] = __builtin_amdgcn_mfma_f32_16x16x32_bf16(a[ms], b[ns], acc[ms][ns], 0, 0, 0);
        }
        __syncthreads();
    }

    bool pv[2];
#pragma unroll
    for (int ns = 0; ns < 2; ++ns)
        pv[ns] = (pixbase + wPix + ns * 16 + l16) < PIX;

    if (out_bf16) {
        ushort* op = (ushort*)outp + ((size_t)np * out_ch + obase) * PIX + pixbase;
#pragma unroll
        for (int ms = 0; ms < 4; ++ms)
#pragma unroll
            for (int ns = 0; ns < 2; ++ns) {
                if (!pv[ns]) continue;
                int pl = wPix + ns * 16 + l16;
#pragma unroll
                for (int r = 0; r < 4; ++r) {
                    int ol = ms * 16 + quad * 4 + r;
                    op[(size_t)ol * PIX + pl] = f2bf(acc[ms][ns][r]);
                }
            }
    } else {
        float* op = (float*)outp + ((size_t)np * out_ch + obase) * PIX + pixbase;
#pragma unroll
        for (int ms = 0; ms < 4; ++ms)
#pragma unroll
            for (int ns = 0; ns < 2; ++ns) {
                if (!pv[ns]) continue;
                int pl = wPix + ns * 16 + l16;
#pragma unroll
                for (int r = 0; r < 4; ++r) {
                    int ol = ms * 16 + quad * 4 + r;
                    op[(size_t)ol * PIX + pl] = acc[ms][ns][r];
                }
            }
    }

    // ---- fused BN stats: per-channel sum / sumsq over this block's tile
    if (stats) {
#pragma unroll
        for (int ms = 0; ms < 4; ++ms)
#pragma unroll
            for (int r = 0; r < 4; ++r) {
                float sv = 0.f, sq = 0.f;
#pragma unroll
                for (int ns = 0; ns < 2; ++ns) {
                    if (pv[ns]) {
                        float z = acc[ms][ns][r];
                        sv += z; sq += z * z;
                    }
                }
#pragma unroll
                for (int m = 1; m < 16; m <<= 1) {
                    sv += __shfl_xor(sv, m);
                    sq += __shfl_xor(sq, m);
                }
                if (l16 == 0) {
                    int ch = obase + ms * 16 + quad * 4 + r;
                    atomicAdd(&stats[ch], sv);
                    atomicAdd(&stats[128 + ch], sq);
                }
            }
    }
}

// ---------------------------------------------------------------------------
// scores via MFMA, TRANSPOSED output: attq[n,s,p][q*64+t] =
//   bf16( attb[t][q] + tanh((Q·K)/800)*alpha )
// ---------------------------------------------------------------------------
__global__ __launch_bounds__(256)
void scores_mfma(const ushort* __restrict__ qk, const float* __restrict__ attb,
                 const float* __restrict__ alphat, ushort* __restrict__ attq)
{
    __shared__ ushort Qs[64 * 128];
    __shared__ ushort Ks[64 * 128];
    const int np = blockIdx.x, s = blockIdx.y, tid = threadIdx.x;
    const int wave = tid >> 6, lane = tid & 63;
    const int quad = lane >> 4, l16 = lane & 15;
    const int qW = (wave >> 1) * 32, tW = (wave & 1) * 32;
    const ushort* qb = qk + ((size_t)np * 192 + s * 64) * PIX;
    const ushort* kb = qb + (size_t)32 * PIX;

    const int side = wave >> 1;
    const int cil = (wave & 1) * 2 + (lane >> 5);   // 0..3 within chunk
    const int t0 = (lane & 31) * 2;
    const ushort* sbase = (side ? kb : qb);
    ushort* dst = side ? Ks : Qs;

    f32x4 acc[2][2];
#pragma unroll
    for (int ms = 0; ms < 2; ++ms)
#pragma unroll
        for (int ns = 0; ns < 2; ++ns)
#pragma unroll
            for (int r = 0; r < 4; ++r) acc[ms][ns][r] = 0.f;

    for (int c = 0; c < 8; ++c) {
        __syncthreads();
        {
            const int ci = c * 4 + cil;
            const ushort* sb = sbase + (size_t)ci * PIX + t0;
            uint u[25];
#pragma unroll
            for (int v = 0; v < 25; ++v)
                u[v] = *(const uint*)(sb + v * 64);
            uint rA[16], rB[16];
#pragma unroll
            for (int w2 = 0; w2 < 12; ++w2) {
                uint a = u[2 * w2], b = u[2 * w2 + 1];
                rA[w2] = (a & 0xffffu) | (b << 16);
                rB[w2] = (a >> 16) | (b & 0xffff0000u);
            }
            rA[12] = u[24] & 0xffffu;  rB[12] = u[24] >> 16;
            rA[13] = 0u; rA[14] = 0u; rA[15] = 0u;
            rB[13] = 0u; rB[14] = 0u; rB[15] = 0u;
#pragma unroll
            for (int b4 = 0; b4 < 4; ++b4) {
                int blkA = (cil * 4 + b4) ^ (t0 & 7);
                int blkB = (cil * 4 + b4) ^ ((t0 + 1) & 7);
                uint4 wa, wb;
                wa.x = rA[b4 * 4 + 0]; wa.y = rA[b4 * 4 + 1];
                wa.z = rA[b4 * 4 + 2]; wa.w = rA[b4 * 4 + 3];
                wb.x = rB[b4 * 4 + 0]; wb.y = rB[b4 * 4 + 1];
                wb.z = rB[b4 * 4 + 2]; wb.w = rB[b4 * 4 + 3];
                *(uint4*)&dst[t0 * 128 + blkA * 8] = wa;
                *(uint4*)&dst[(t0 + 1) * 128 + blkB * 8] = wb;
            }
        }
        __syncthreads();
#pragma unroll
        for (int ks = 0; ks < 4; ++ks) {
            short8 a[2], b[2];
#pragma unroll
            for (int ms = 0; ms < 2; ++ms) {
                int q = qW + ms * 16 + l16;
                int blk = (ks * 4 + quad) ^ (q & 7);
                a[ms] = *(const short8*)&Ks[q * 128 + blk * 8];
            }
#pragma unroll
            for (int ns = 0; ns < 2; ++ns) {
                int t = tW + ns * 16 + l16;
                int blk = (ks * 4 + quad) ^ (t & 7);
                b[ns] = *(const short8*)&Qs[t * 128 + blk * 8];
            }
#pragma unroll
            for (int ms = 0; ms < 2; ++ms)
#pragma unroll
                for (int ns = 0; ns < 2; ++ns)
                    acc[ms][ns] = __builtin_amdgcn_mfma_f32_16x16x32_bf16(a[ms], b[ns], acc[ms][ns], 0, 0, 0);
        }
    }

    const float alpha = alphat[s];
    const int n = np / 6, p = np % 6;
    const float* bp2 = attb + (size_t)s * 4096;
    ushort* ap = attq + ((size_t)(n * SS + s) * 6 + p) * 4096;
    const float inv = 1.0f / 800.0f;
#pragma unroll
    for (int ms = 0; ms < 2; ++ms)
#pragma unroll
        for (int ns = 0; ns < 2; ++ns) {
            int t = tW + ns * 16 + l16;
#pragma unroll
            for (int r = 0; r < 4; ++r) {
                int q = qW + ms * 16 + quad * 4 + r;
                ap[q * 64 + t] = f2bf(bp2[t * 64 + q] + tanhf(acc[ms][ns][r] * inv) * alpha);
            }
        }
}

// ---------------------------------------------------------------------------
// Fused attention-apply + output conv + BN stats.
//  Per block (np, v): Z[np][o][v*64+q] = b_out[o] +
//     sum_s sum_c W_out[o][s*128+c] * ( sum_t xr[np][c][v*64+t] * att_s[t][q] )
//  Ta and W operands are read as MFMA fragments DIRECTLY from global (both
//  L1/L2-resident) — no LDS staging, no stage barrier. Only Xa (coalescing)
//  and Ys (cross-lane c<->q redistribution) use LDS. 2 barriers per s-iter.
//  LDS = 16K + 16K = 32768 B. BN sum/sumsq fused via wave-reduce + atomics.
// ---------------------------------------------------------------------------
__global__ __launch_bounds__(256, 4)
void attn_conv(const ushort* __restrict__ xr, const ushort* __restrict__ attq,
               const ushort* __restrict__ Wo, const float* __restrict__ bias,
               float* __restrict__ Z, float* __restrict__ stats)
{
    __shared__ ushort Xa[128 * 64];   // [c][t] swizzled
    __shared__ ushort Ys[64 * 128];   // [q][c] swizzled
    const int np = blockIdx.x, v = blockIdx.y;
    const int tid = threadIdx.x;
    const int wave = tid >> 6, lane = tid & 63;
    const int quad = lane >> 4, l16 = lane & 15;
    const int mH = (wave & 1) * 64;    // GEMM1 c-half
    const int oH = (wave & 1) * 64;    // GEMM2 o-half
    const int qH = (wave >> 1) * 32;   // q-half (both GEMMs)
    const int n = np / 6, p = np % 6;

    // ---- stage Xa[c][t] once (coalesced, swizzled b128 writes)
    {
        int cc = tid >> 1, half = tid & 1;
        const ushort* src = xr + ((size_t)np * 128 + cc) * PIX + v * 64 + half * 32;
        uint4 a = *(const uint4*)src;
        uint4 b = *(const uint4*)(src + 8);
        uint4 c0 = *(const uint4*)(src + 16);
        uint4 d = *(const uint4*)(src + 24);
        int sw = cc & 7;
        ushort* xb = &Xa[cc * 64];
        *(uint4*)&xb[((half * 4 + 0) ^ sw) * 8] = a;
        *(uint4*)&xb[((half * 4 + 1) ^ sw) * 8] = b;
        *(uint4*)&xb[((half * 4 + 2) ^ sw) * 8] = c0;
        *(uint4*)&xb[((half * 4 + 3) ^ sw) * 8] = d;
    }

    // ---- init Z accumulators with bias (o = oH + ms2*16 + quad*4 + r)
    f32x4 acc2[4][2];
#pragma unroll
    for (int ms2 = 0; ms2 < 4; ++ms2) {
        float bv[4];
#pragma unroll
        for (int r = 0; r < 4; ++r)
            bv[r] = bias[oH + ms2 * 16 + quad * 4 + r];
#pragma unroll
        for (int ns = 0; ns < 2; ++ns)
#pragma unroll
            for (int r = 0; r < 4; ++r) acc2[ms2][ns][r] = bv[r];
    }

    const ushort* tb0 = attq + ((size_t)(n * SS) * 6 + p) * 4096;
    __syncthreads();   // Xa visible

    for (int s = 0; s < SS; ++s) {
        // ---- GEMM1: Y = Xa(LDS) x Ta(global, L1-resident fragments)
        const ushort* ts = tb0 + (size_t)s * 6 * 4096;
        f32x4 acc[4][2];
#pragma unroll
        for (int ms = 0; ms < 4; ++ms)
#pragma unroll
            for (int ns = 0; ns < 2; ++ns)
#pragma unroll
                for (int r = 0; r < 4; ++r) acc[ms][ns][r] = 0.f;
#pragma unroll
        for (int ks = 0; ks < 2; ++ks) {
            short8 a[4], b[2];
#pragma unroll
            for (int ns = 0; ns < 2; ++ns)
                b[ns] = *(const short8*)(ts + (size_t)(qH + ns * 16 + l16) * 64 + ks * 32 + quad * 8);
#pragma unroll
            for (int ms = 0; ms < 4; ++ms) {
                int row = mH + ms * 16 + l16;
                int blk = (ks * 4 + quad) ^ (l16 & 7);
                a[ms] = *(const short8*)&Xa[row * 64 + blk * 8];
            }
#pragma unroll
            for (int ms = 0; ms < 4; ++ms)
#pragma unroll
                for (int ns = 0; ns < 2; ++ns)
                    acc[ms][ns] = __builtin_amdgcn_mfma_f32_16x16x32_bf16(a[ms], b[ns], acc[ms][ns], 0, 0, 0);
        }
        __syncthreads();   // all waves done reading Ys(s-1) (noop effect at s=0)
        // ---- write Ys[q][c] bf16, swizzled
#pragma unroll
        for (int ms = 0; ms < 4; ++ms)
#pragma unroll
            for (int ns = 0; ns < 2; ++ns) {
                int q = qH + ns * 16 + l16;
                int c0 = mH + ms * 16 + quad * 4;
                uint w0 = (uint)f2bf(acc[ms][ns][0]) | ((uint)f2bf(acc[ms][ns][1]) << 16);
                uint w1 = (uint)f2bf(acc[ms][ns][2]) | ((uint)f2bf(acc[ms][ns][3]) << 16);
                int blk = (c0 >> 3) ^ (q & 7);
                ushort* d = &Ys[q * 128 + blk * 8 + (c0 & 7)];
                *(uint*)d = w0;
                *(uint*)(d + 2) = w1;
            }
        __syncthreads();
        // ---- GEMM2: Z += W(global) x Ys(LDS)
#pragma unroll
        for (int ks2 = 0; ks2 < 4; ++ks2) {
            short8 wfa[4];
            const ushort* wb = Wo + (size_t)(oH + l16) * 384 + s * 128 + ks2 * 32 + quad * 8;
#pragma unroll
            for (int ms2 = 0; ms2 < 4; ++ms2)
                wfa[ms2] = *(const short8*)(wb + (size_t)ms2 * 16 * 384);
            short8 b2[2];
#pragma unroll
            for (int ns = 0; ns < 2; ++ns) {
                int q = qH + ns * 16 + l16;
                int blk = (ks2 * 4 + quad) ^ (q & 7);
                b2[ns] = *(const short8*)&Ys[q * 128 + blk * 8];
            }
#pragma unroll
            for (int ms2 = 0; ms2 < 4; ++ms2)
#pragma unroll
                for (int ns = 0; ns < 2; ++ns)
                    acc2[ms2][ns] = __builtin_amdgcn_mfma_f32_16x16x32_bf16(wfa[ms2], b2[ns], acc2[ms2][ns], 0, 0, 0);
        }
    }

    // ---- epilogue: write Z fp32 + fused BN stats
    float* zp = Z + (size_t)np * 128 * PIX + v * 64;
#pragma unroll
    for (int ms2 = 0; ms2 < 4; ++ms2)
#pragma unroll
        for (int ns = 0; ns < 2; ++ns) {
            int q = qH + ns * 16 + l16;
#pragma unroll
            for (int r = 0; r < 4; ++r) {
                int o = oH + ms2 * 16 + quad * 4 + r;
                zp[(size_t)o * PIX + q] = acc2[ms2][ns][r];
            }
        }
#pragma unroll
    for (int ms2 = 0; ms2 < 4; ++ms2)
#pragma unroll
        for (int r = 0; r < 4; ++r) {
            float sv = acc2[ms2][0][r] + acc2[ms2][1][r];
            float sq = acc2[ms2][0][r] * acc2[ms2][0][r]
                     + acc2[ms2][1][r] * acc2[ms2][1][r];
#pragma unroll
            for (int m = 1; m < 16; m <<= 1) {
                sv += __shfl_xor(sv, m);
                sq += __shfl_xor(sq, m);
            }
            if (l16 == 0) {
                int o = oH + ms2 * 16 + quad * 4 + r;
                atomicAdd(&stats[o], sv);
                atomicAdd(&stats[128 + o], sq);
            }
        }
}

// ---------------------------------------------------------------------------
__global__ void bn_finalize(const float* __restrict__ stats, const float* __restrict__ g,
                            const float* __restrict__ be, float* __restrict__ scsh) {
    const int c = threadIdx.x;
    float mean = stats[c] * (1.0f / EPC);
    float var = stats[128 + c] * (1.0f / EPC) - mean * mean;
    float inv = rsqrtf(var + 1e-5f);
    float sc = g[c] * inv;
    scsh[c] = sc;
    scsh[128 + c] = be[c] - mean * sc;
}

// ---------------------------------------------------------------------------
// res1: y1 = leaky(x + bn(Z')), fp32 out + bf16 copy (same rounding as before)
// ---------------------------------------------------------------------------
__global__ void res_bn_g(const float* __restrict__ x, const float* __restrict__ z,
                         const float* __restrict__ scsh, float* __restrict__ out,
                         ushort* __restrict__ outb) {
    size_t i = ((size_t)blockIdx.x * 256 + threadIdx.x) * 4;
    size_t row = i / PIX;
    int p = (int)(i % PIX);
    int ch = (int)(row & 127);
    float sc = scsh[ch], sh = scsh[128 + ch];
    const float* zr = z + row * PIX;
    float4 a = *(const float4*)(x + i);
    float xin[4] = {a.x, a.y, a.z, a.w};
    float4 r;
    float ro[4];
#pragma unroll
    for (int j = 0; j < 4; ++j) {
        int pp = p + j;
        int t = pp / 25, vv = pp - t * 25;
        float zz = zr[vv * 64 + t];
        float val = xin[j] + fmaf(zz, sc, sh);
        ro[j] = val >= 0.f ? val : 0.1f * val;
    }
    r.x = ro[0]; r.y = ro[1]; r.z = ro[2]; r.w = ro[3];
    *(float4*)(out + i) = r;
    uint2 ub;
    ub.x = (uint)f2bf(ro[0]) | ((uint)f2bf(ro[1]) << 16);
    ub.y = (uint)f2bf(ro[2]) | ((uint)f2bf(ro[3]) << 16);
    *(uint2*)(outb + i) = ub;
}

// ---------------------------------------------------------------------------
// res2: out = leaky(y1 + bn(z2)), all orig order, float4
// ---------------------------------------------------------------------------
__global__ void res_bn_l(const float4* __restrict__ xr, const float4* __restrict__ zr,
                         const float* __restrict__ scsh, float4* __restrict__ out) {
    int i = blockIdx.x * 256 + threadIdx.x;
    int row = i / 400;
    int ch = row & 127;
    float sc = scsh[ch], sh = scsh[128 + ch];
    float4 a = xr[i], b = zr[i], r;
    r.x = a.x + fmaf(b.x, sc, sh);
    r.y = a.y + fmaf(b.y, sc, sh);
    r.z = a.z + fmaf(b.z, sc, sh);
    r.w = a.w + fmaf(b.w, sc, sh);
    r.x = r.x >= 0.f ? r.x : 0.1f * r.x;
    r.y = r.y >= 0.f ? r.y : 0.1f * r.y;
    r.z = r.z >= 0.f ? r.z : 0.1f * r.z;
    r.w = r.w >= 0.f ? r.w : 0.1f * r.w;
    out[i] = r;
}

// ---------------------------------------------------------------------------
struct Ctx {
    ushort *xr, *Wp, *Wo, *Wf, *ATTQ;
    float *bp;
    float *R1, *R0, *STATS;
    const float *alphat, *b_out, *g_out, *be_out, *b_ff, *g_ff, *be_ff;
};

static void run_block(const float* X, const float* attb, float* OUT,
                      const Ctx& c, hipStream_t stream) {
    const int EG = 38400;   // 39,321,600 / (256*4)
    remap_x<<<EG, 256, 0, stream>>>(X, c.xr);
    // q/k conv -> QK (bf16, in R1), channels [q0|k0|q1|k1|q2|k2]
    gemm_conv<<<dim3(NPB, 13, 3), 256, 0, stream>>>(c.xr, 1, c.Wp, 128, c.bp,
                                                    (void*)c.R1, 1, 192, nullptr);
    scores_mfma<<<dim3(NPB, 3), 256, 0, stream>>>((const ushort*)c.R1, attb, c.alphat, c.ATTQ);
    // fused attention-apply + output conv + BN1 stats, Z in R0
    hipMemsetAsync(c.STATS, 0, 256 * sizeof(float), stream);
    attn_conv<<<dim3(NPB, VV), 256, 0, stream>>>(c.xr, c.ATTQ, c.Wo, c.b_out,
                                                 c.R0, c.STATS);
    bn_finalize<<<1, 128, 0, stream>>>(c.STATS, c.g_out, c.be_out, c.STATS + 256);
    // y1 fp32 in R1, y1 bf16 in xr (xr is dead for the rest of this block)
    res_bn_g<<<EG, 256, 0, stream>>>(X, c.R0, c.STATS + 256, c.R1, c.xr);
    hipMemsetAsync(c.STATS, 0, 256 * sizeof(float), stream);
    gemm_conv<<<dim3(NPB, 13, 2), 256, 0, stream>>>(c.xr, 1, c.Wf, 128, c.b_ff,
                                                    (void*)c.R0, 0, 128, c.STATS);
    bn_finalize<<<1, 128, 0, stream>>>(c.STATS, c.g_ff, c.be_ff, c.STATS + 256);
    res_bn_l<<<EG, 256, 0, stream>>>((const float4*)c.R1, (const float4*)c.R0,
                                     c.STATS + 256, (float4*)OUT);
}

extern "C" void kernel_launch(void* const* d_in, const int* in_sizes, int n_in,
                              void* d_out, int out_size, void* d_ws, size_t ws_size,
                              hipStream_t stream) {
    const float* x = (const float*)d_in[0];
    const float* att1 = (const float*)d_in[1];
    const float* att2 = (const float*)d_in[2];
    Ctx c;
    c.alphat = (const float*)d_in[3];
    const float* w_in = (const float*)d_in[4];
    const float* b_in = (const float*)d_in[5];
    const float* w_out = (const float*)d_in[6];
    c.b_out = (const float*)d_in[7];
    c.g_out = (const float*)d_in[8];
    c.be_out = (const float*)d_in[9];
    const float* w_ff = (const float*)d_in[10];
    c.b_ff = (const float*)d_in[11];
    c.g_ff = (const float*)d_in[12];
    c.be_ff = (const float*)d_in[13];

    char* ws = (char*)d_ws;
    size_t off = 0;
    c.xr = (ushort*)(ws + off);   off += ETOT * 2;                    //  78.6 MB
    c.R1 = (float*)(ws + off);    off += ETOT * 4;                    // 157.3 MB
    c.R0 = (float*)(ws + off);    off += ETOT * 4;                    // 157.3 MB
    c.ATTQ = (ushort*)(ws + off); off += (size_t)32 * 3 * 6 * 4096 * 2; // 4.7 MB
    c.STATS = (float*)(ws + off); off += 512 * 4;
    c.Wp = (ushort*)(ws + off);   off += 192 * 128 * 2;
    c.bp = (float*)(ws + off);    off += 192 * 4;
    c.Wo = (ushort*)(ws + off);   off += 128 * 384 * 2;
    c.Wf = (ushort*)(ws + off);   off += 128 * 128 * 2;

    wprep<<<192, 256, 0, stream>>>(w_in, b_in, w_out, w_ff, c.Wp, c.bp, c.Wo, c.Wf);

    float* out = (float*)d_out;
    run_block(x, att1, out, c, stream);
    run_block(out, att2, out, c, stream);
}